// Round 2
// baseline (3157.097 us; speedup 1.0000x reference)
//
#include <hip/hip_runtime.h>
#include <stdint.h>

#define BB 2
#define NN 8192
#define MM 2048
#define CIN_ 64
#define COUT_ 128
#define LPC_ 16
#define NS_ 32
#define KSEL 160
#define EPSB 1e-5f

// ws layout (float offsets)
#define WS_IDX    0         // int[B*M]
#define WS_IDXK   4096      // int[B*KSEL]
#define WS_LOGIT  4416      // f[B*M]
#define WS_ATT    8512      // f[B*M]
#define WS_FIT    16384     // f[B*M*64]
#define WS_IDT    278528    // f[B*M*128]
#define WS_A1S    802816    // f[B*M*16]
#define WS_VT     868352    // f[B*KSEL*64]
#define WS_B1S    888832    // f[B*KSEL*16]
#define WS_GFT    893952    // f[B*M*128]
#define WS_FPOST  1418240   // f[B*N*128]
#define WS_GIDX   3515392   // int[B*M*32]

#define OUT_NEWP 0
#define OUT_LPI  12288
#define OUT_F    77824

__device__ __forceinline__ float dist2_rn(float ax, float ay, float az,
                                          float bx, float by, float bz) {
  float dx = __fsub_rn(ax, bx);
  float dy = __fsub_rn(ay, by);
  float dz = __fsub_rn(az, bz);
  return __fadd_rn(__fadd_rn(__fmul_rn(dx, dx), __fmul_rn(dy, dy)), __fmul_rn(dz, dz));
}

// ------------------------------------------------------------------
// K1: farthest point sampling, one block per batch.
// ------------------------------------------------------------------
#define PPT 8
__global__ __launch_bounds__(1024) void k_fps(const float* __restrict__ p,
                                              int* __restrict__ idx_out,
                                              float* __restrict__ newp_out) {
  __shared__ unsigned int hist[4096];
  __shared__ unsigned int perm[NN];
  __shared__ unsigned long long slots[16];
  __shared__ float slotx[16], sloty[16], slotz[16];
  __shared__ unsigned int wsum[16];

  const int b = blockIdx.x;
  const float* pb = p + b * NN * 3;
  const int tid = threadIdx.x;
  const int lane = tid & 63;
  const int wid = tid >> 6;

  // --- 1. histogram of 16^3 cells ---
  for (int i = tid; i < 4096; i += 1024) hist[i] = 0u;
  __syncthreads();

  int cellv[PPT];
  #pragma unroll
  for (int k = 0; k < PPT; k++) {
    int i = tid + k * 1024;
    float x = pb[i * 3 + 0], y = pb[i * 3 + 1], z = pb[i * 3 + 2];
    int cx = (int)(x * 16.f); cx = cx < 0 ? 0 : (cx > 15 ? 15 : cx);
    int cy = (int)(y * 16.f); cy = cy < 0 ? 0 : (cy > 15 ? 15 : cy);
    int cz = (int)(z * 16.f); cz = cz < 0 ? 0 : (cz > 15 ? 15 : cz);
    int c = (cz * 16 + cy) * 16 + cx;
    cellv[k] = c;
    atomicAdd(&hist[c], 1u);
  }
  __syncthreads();

  // --- 2. exclusive scan over 4096 bins (thread owns 4) ---
  unsigned int h0 = hist[tid * 4 + 0], h1 = hist[tid * 4 + 1];
  unsigned int h2 = hist[tid * 4 + 2], h3 = hist[tid * 4 + 3];
  unsigned int s = h0 + h1 + h2 + h3;
  unsigned int pre = s;
  for (int d = 1; d < 64; d <<= 1) {
    unsigned int o = (unsigned int)__shfl_up((int)pre, d);
    if (lane >= d) pre += o;
  }
  if (lane == 63) wsum[wid] = pre;
  __syncthreads();
  if (tid < 16) {
    unsigned int v = wsum[tid];
    unsigned int q = v;
    for (int d = 1; d < 16; d <<= 1) {
      unsigned int o = (unsigned int)__shfl_up((int)q, d);
      if (tid >= d) q += o;
    }
    wsum[tid] = q - v;  // exclusive
  }
  __syncthreads();
  unsigned int base = wsum[wid] + (pre - s);
  hist[tid * 4 + 0] = base;
  hist[tid * 4 + 1] = base + h0;
  hist[tid * 4 + 2] = base + h0 + h1;
  hist[tid * 4 + 3] = base + h0 + h1 + h2;
  __syncthreads();

  // --- 3. scatter permutation ---
  #pragma unroll
  for (int k = 0; k < PPT; k++) {
    unsigned int pos = atomicAdd(&hist[cellv[k]], 1u);
    perm[pos] = (unsigned int)(tid + k * 1024);
  }
  __syncthreads();

  // --- 4. load sorted points into registers + bbox ---
  float sx[PPT], sy[PPT], sz[PPT], dist[PPT];
  unsigned int lov[PPT];
  float bxmin = 1e30f, bymin = 1e30f, bzmin = 1e30f;
  float bxmax = -1e30f, bymax = -1e30f, bzmax = -1e30f;
  #pragma unroll
  for (int q = 0; q < PPT; q++) {
    unsigned int o = perm[tid * PPT + q];
    float x = pb[o * 3 + 0], y = pb[o * 3 + 1], z = pb[o * 3 + 2];
    sx[q] = x; sy[q] = y; sz[q] = z;
    lov[q] = ((8191u - o) << 3) | (unsigned int)q;
    dist[q] = 1e10f;
    bxmin = fminf(bxmin, x); bxmax = fmaxf(bxmax, x);
    bymin = fminf(bymin, y); bymax = fmaxf(bymax, y);
    bzmin = fminf(bzmin, z); bzmax = fmaxf(bzmax, z);
  }

  // first winner: original index 0
  float wx = pb[0], wy = pb[1], wz = pb[2];
  if (tid == 0) {
    newp_out[(b * MM + 0) * 3 + 0] = wx;
    newp_out[(b * MM + 0) * 3 + 1] = wy;
    newp_out[(b * MM + 0) * 3 + 2] = wz;
    idx_out[b * MM + 0] = 0;
  }
  if (tid < 16) { slots[tid] = 0ull; slotx[tid] = 0.f; sloty[tid] = 0.f; slotz[tid] = 0.f; }
  // CRITICAL: thrPack must start with dist=1e10 (matching dist[] init) so every
  // lane is active at t=1.  Starting at 0 made bd<thrMax false for all threads
  // and the whole FPS produced zeros (round-1 absmax=1.0 failure).
  unsigned long long thrPack = ((unsigned long long)__float_as_uint(1e10f) << 32);
  __syncthreads();

  for (int t = 1; t < MM; t++) {
    // bbox-based exact skip test
    float ex = fmaxf(fmaxf(bxmin - wx, wx - bxmax), 0.f);
    float ey = fmaxf(fmaxf(bymin - wy, wy - bymax), 0.f);
    float ez = fmaxf(fmaxf(bzmin - wz, wz - bzmax), 0.f);
    float bd = (ex * ex + ey * ey + ez * ez) * 0.999f;  // conservative margin
    float thrMax = __uint_as_float((unsigned int)(thrPack >> 32));
    bool active = (bd < thrMax);
    unsigned long long wmask = __ballot(active);
    if (wmask) {
      if (active) {
        unsigned long long best = 0ull;
        #pragma unroll
        for (int q = 0; q < PPT; q++) {
          float d = dist2_rn(sx[q], sy[q], sz[q], wx, wy, wz);
          float nd = fminf(dist[q], d);
          dist[q] = nd;
          unsigned long long pk =
              ((unsigned long long)__float_as_uint(nd) << 32) | (unsigned long long)lov[q];
          best = pk > best ? pk : best;
        }
        thrPack = best;
      }
      // wave reduce (all lanes contribute, inactive lanes keep old max)
      unsigned long long wp = thrPack;
      for (int off = 32; off; off >>= 1) {
        unsigned long long o = __shfl_xor(wp, off);
        wp = o > wp ? o : wp;
      }
      if (thrPack == wp) {
        slots[wid] = wp;
        #pragma unroll
        for (int q = 0; q < PPT; q++) {
          if ((unsigned int)(wp & 7ull) == (unsigned int)q) {
            slotx[wid] = sx[q]; sloty[wid] = sy[q]; slotz[wid] = sz[q];
          }
        }
      }
    }
    __syncthreads();  // slots published

    // cross-wave reduce (redundant in every wave)
    int sidx = lane & 15;
    unsigned long long sp = slots[sidx];
    float cx = slotx[sidx], cy = sloty[sidx], cz = slotz[sidx];
    unsigned long long w2 = sp;
    for (int off = 8; off; off >>= 1) {
      unsigned long long o = __shfl_xor(w2, off);
      w2 = o > w2 ? o : w2;
    }
    unsigned long long bal = __ballot(sp == w2);
    int src = __ffsll((unsigned long long)bal) - 1;
    wx = __shfl(cx, src);
    wy = __shfl(cy, src);
    wz = __shfl(cz, src);
    if (tid == 0) {
      int worig = 8191 - (int)((w2 >> 3) & 0x1FFFull);
      newp_out[(b * MM + t) * 3 + 0] = wx;
      newp_out[(b * MM + t) * 3 + 1] = wy;
      newp_out[(b * MM + t) * 3 + 2] = wz;
      idx_out[b * MM + t] = worig;
    }
    __syncthreads();  // protect slots before next writes
  }
}

// ------------------------------------------------------------------
// K2a: gather lpi (to d_out), fi (transposed), logits + att
// ------------------------------------------------------------------
__global__ __launch_bounds__(256) void k_gather(const float* __restrict__ lp,
                                                const float* __restrict__ f,
                                                const int* __restrict__ idx,
                                                const float* __restrict__ Wg,
                                                const float* __restrict__ bg,
                                                float* __restrict__ fiT,
                                                float* __restrict__ logit,
                                                float* __restrict__ att,
                                                float* __restrict__ out_lpi) {
  int gm = blockIdx.x * 256 + threadIdx.x;
  if (gm >= BB * MM) return;
  int b = gm >> 11, m = gm & 2047;
  int j = idx[gm];
  const float* lpb = lp + b * LPC_ * NN;
  float* olpi = out_lpi + b * LPC_ * MM;
  #pragma unroll
  for (int c = 0; c < LPC_; c++) olpi[c * MM + m] = lpb[c * NN + j];
  const float* fb = f + b * CIN_ * NN;
  float lg = bg[0];
  #pragma unroll
  for (int c = 0; c < CIN_; c++) {
    float x = fb[c * NN + j];
    fiT[gm * 64 + c] = x;
    lg = __fadd_rn(lg, __fmul_rn(Wg[c], x));
  }
  logit[gm] = lg;
  att[gm] = 1.f / (1.f + expf(-lg));
}

// ------------------------------------------------------------------
// K2b: identity = W_skip @ fi + b_skip
// ------------------------------------------------------------------
__global__ __launch_bounds__(256) void k_ident(const float* __restrict__ fiT,
                                               const float* __restrict__ Wskip,
                                               const float* __restrict__ bskip,
                                               float* __restrict__ idT) {
  int gt = blockIdx.x * 256 + threadIdx.x;
  if (gt >= BB * MM * 16) return;
  int og = gt & 15, gm = gt >> 4;
  const float* fvp = fiT + gm * 64;
  float fv[64];
  #pragma unroll
  for (int c = 0; c < 64; c++) fv[c] = fvp[c];
  #pragma unroll
  for (int q = 0; q < 8; q++) {
    int o = og * 8 + q;
    float a = bskip[o];
    #pragma unroll
    for (int c = 0; c < 64; c++) a = fmaf(Wskip[o * 64 + c], fv[c], a);
    idT[gm * 128 + o] = a;
  }
}

// ------------------------------------------------------------------
// K3: top-160 per batch — bitonic sort of (att desc, idx asc) keys.
// Sort on att (not logit): sigmoid is non-injective in f32, and top_k
// breaks att-ties by smallest index.
// ------------------------------------------------------------------
__global__ __launch_bounds__(1024) void k_topk(const float* __restrict__ att,
                                               int* __restrict__ idxk) {
  __shared__ unsigned long long key[MM];
  int b = blockIdx.x, tid = threadIdx.x;
  for (int i = tid; i < MM; i += 1024) {
    unsigned int u = __float_as_uint(att[b * MM + i]);
    u ^= (u & 0x80000000u) ? 0xFFFFFFFFu : 0x80000000u;  // monotone asc
    u = ~u;                                              // descending
    key[i] = ((unsigned long long)u << 32) | (unsigned int)i;
  }
  __syncthreads();
  for (int k = 2; k <= MM; k <<= 1) {
    for (int j = k >> 1; j > 0; j >>= 1) {
      for (int i = tid; i < MM; i += 1024) {
        int ixj = i ^ j;
        if (ixj > i) {
          bool up = (i & k) == 0;
          unsigned long long a = key[i], c = key[ixj];
          if ((a > c) == up) { key[i] = c; key[ixj] = a; }
        }
      }
      __syncthreads();
    }
  }
  if (tid < KSEL) idxk[b * KSEL + tid] = (int)(key[tid] & 0xFFFFFFFFull);
}

// ------------------------------------------------------------------
// K4a: A1s[c1,m] = s1*( (W_w1 @ (fi*att))[c1,m] ) + t1
// ------------------------------------------------------------------
__global__ __launch_bounds__(256) void k_a1s(const float* __restrict__ fiT,
                                             const float* __restrict__ att,
                                             const float* __restrict__ Ww1,
                                             const float* __restrict__ bnw1,
                                             float* __restrict__ a1sT) {
  int gm = blockIdx.x * 256 + threadIdx.x;
  if (gm >= BB * MM) return;
  const float* fvp = fiT + gm * 64;
  float a = att[gm];
  float fv[64];
  #pragma unroll
  for (int c = 0; c < 64; c++) fv[c] = fvp[c] * a;
  #pragma unroll
  for (int c1 = 0; c1 < 16; c1++) {
    float acc = 0.f;
    #pragma unroll
    for (int c = 0; c < 64; c++) acc = fmaf(Ww1[c1 * 64 + c], fv[c], acc);
    float g = bnw1[c1], be = bnw1[16 + c1], mu = bnw1[32 + c1], va = bnw1[48 + c1];
    float sc = g / sqrtf(va + EPSB);
    a1sT[gm * 16 + c1] = acc * sc + (be - mu * sc);
  }
}

// ------------------------------------------------------------------
// K4b: sparse columns -> v and B1s
// ------------------------------------------------------------------
__global__ __launch_bounds__(256) void k_vb1(const float* __restrict__ fiT,
                                             const int* __restrict__ idxk,
                                             const float* __restrict__ Wv,
                                             const float* __restrict__ bv,
                                             const float* __restrict__ Ww1,
                                             const float* __restrict__ bnw1,
                                             float* __restrict__ vT,
                                             float* __restrict__ b1sT) {
  int gk = blockIdx.x * 256 + threadIdx.x;
  if (gk >= BB * KSEL) return;
  int b = gk / KSEL;
  int kk = idxk[gk];
  const float* fvp = fiT + (b * MM + kk) * 64;
  float fv[64];
  #pragma unroll
  for (int c = 0; c < 64; c++) fv[c] = fvp[c];
  for (int o = 0; o < 64; o++) {
    float acc = bv[o];
    #pragma unroll
    for (int c = 0; c < 64; c++) acc = fmaf(Wv[o * 64 + c], fv[c], acc);
    vT[gk * 64 + o] = acc;
  }
  #pragma unroll
  for (int c1 = 0; c1 < 16; c1++) {
    float acc = 0.f;
    #pragma unroll
    for (int c = 0; c < 64; c++) acc = fmaf(Ww1[c1 * 64 + c], fv[c], acc);
    float g = bnw1[c1], va = bnw1[48 + c1];
    b1sT[gk * 16 + c1] = acc * (g / sqrtf(va + EPSB));
  }
}

// ------------------------------------------------------------------
// K5: fused attention epilogue + global_f.  one wave per (b,m), lane = c2
// ------------------------------------------------------------------
__global__ __launch_bounds__(256) void k_att(const float* __restrict__ a1sT,
                                             const float* __restrict__ b1sT,
                                             const float* __restrict__ vT,
                                             const float* __restrict__ fiT,
                                             const float* __restrict__ Ww2,
                                             const float* __restrict__ bw2,
                                             const float* __restrict__ Wm,
                                             const float* __restrict__ bnm,
                                             float* __restrict__ gfT) {
  __shared__ float B1sh[KSEL * 16];
  __shared__ float dsh[4][64];
  int b = blockIdx.x >> 9;
  const float* bsrc = b1sT + b * KSEL * 16;
  for (int i = threadIdx.x; i < KSEL * 16; i += 256) B1sh[i] = bsrc[i];
  __syncthreads();
  int wid = threadIdx.x >> 6, lane = threadIdx.x & 63;
  int gm = blockIdx.x * 4 + wid;
  int c15 = lane & 15;
  float a1 = a1sT[gm * 16 + c15];
  float wrow[16];
  #pragma unroll
  for (int c = 0; c < 16; c++) wrow[c] = Ww2[lane * 16 + c];
  float bw = bw2[lane];
  const float* vp = vT + b * KSEL * 64 + lane;
  float acc = 0.f;
  for (int k = 0; k < KSEL; k++) {
    float t = fmaxf(a1 - B1sh[k * 16 + c15], 0.f);
    float r2 = bw;
    #pragma unroll
    for (int c = 0; c < 16; c++) {
      float tc = __int_as_float(__builtin_amdgcn_readlane(__float_as_int(t), c));
      r2 = fmaf(wrow[c], tc, r2);
    }
    acc = fmaf(fmaxf(r2, 0.f), vp[k * 64], acc);
  }
  float af = acc * (1.f / (float)KSEL);
  float d = af - fiT[gm * 64 + lane];
  dsh[wid][lane] = d;
  __syncthreads();
  #pragma unroll
  for (int t2 = 0; t2 < 2; t2++) {
    int o = lane + t2 * 64;
    float g = 0.f;
    #pragma unroll
    for (int c = 0; c < 64; c++) g = fmaf(Wm[o * 64 + c], dsh[wid][c], g);
    float ga = bnm[o], be = bnm[COUT_ + o], mu = bnm[2 * COUT_ + o], va = bnm[3 * COUT_ + o];
    float sc = ga / sqrtf(va + EPSB);
    gfT[gm * 128 + o] = fmaxf(g * sc + (be - mu * sc), 0.f);
  }
}

// ------------------------------------------------------------------
// K6: fpost = relu(bn(W_post @ f))  stored transposed (b, n, 128)
// ------------------------------------------------------------------
__global__ __launch_bounds__(256) void k_fpost(const float* __restrict__ f,
                                               const float* __restrict__ Wpost,
                                               const float* __restrict__ bnpost,
                                               float* __restrict__ fpostT) {
  int gt = blockIdx.x * 256 + threadIdx.x;
  if (gt >= BB * NN * 16) return;
  int og = gt & 15, nn = gt >> 4;
  int b = nn >> 13, n = nn & 8191;
  const float* fb = f + b * CIN_ * NN + n;
  float acc[8];
  #pragma unroll
  for (int q = 0; q < 8; q++) acc[q] = 0.f;
  for (int c = 0; c < 64; c++) {
    float x = fb[c * NN];
    #pragma unroll
    for (int q = 0; q < 8; q++) acc[q] = fmaf(Wpost[(og * 8 + q) * 64 + c], x, acc[q]);
  }
  #pragma unroll
  for (int q = 0; q < 8; q++) {
    int o = og * 8 + q;
    float ga = bnpost[o], be = bnpost[COUT_ + o], mu = bnpost[2 * COUT_ + o], va = bnpost[3 * COUT_ + o];
    float sc = ga / sqrtf(va + EPSB);
    fpostT[(b * NN + n) * 128 + o] = fmaxf(acc[q] * sc + (be - mu * sc), 0.f);
  }
}

// ------------------------------------------------------------------
// K7: ball query, one wave per (b,m)
// ------------------------------------------------------------------
__global__ __launch_bounds__(256) void k_ball(const float* __restrict__ p,
                                              const float* __restrict__ newp,
                                              int* __restrict__ gidx) {
  int wid = threadIdx.x >> 6, lane = threadIdx.x & 63;
  int gm = blockIdx.x * 4 + wid;
  int b = gm >> 11;
  const float* q = newp + gm * 3;
  float qx = q[0], qy = q[1], qz = q[2];
  const float* pb = p + b * NN * 3;
  int* out = gidx + gm * NS_;
  const float RR = (float)(0.1 * 0.1);  // matches f32(double 0.01)
  int cnt = 0, firstj = 0;
  bool haveFirst = false;
  for (int chunk = 0; chunk < NN / 64 && cnt < NS_; chunk++) {
    int j = chunk * 64 + lane;
    float d = dist2_rn(qx, qy, qz, pb[j * 3], pb[j * 3 + 1], pb[j * 3 + 2]);
    unsigned long long mask = __ballot(d < RR);
    while (mask && cnt < NS_) {
      int l = __ffsll(mask) - 1;
      mask &= mask - 1;
      int jj = chunk * 64 + l;
      if (!haveFirst) { firstj = jj; haveFirst = true; }
      if (lane == 0) out[cnt] = jj;
      cnt++;
    }
  }
  if (lane == 0) {
    for (int i = cnt; i < NS_; i++) out[i] = firstj;
  }
}

// ------------------------------------------------------------------
// K8: grouped local conv + max + final combine -> d_out fout
// ------------------------------------------------------------------
__global__ __launch_bounds__(128) void k_final(const float* __restrict__ lp,
                                               const float* __restrict__ lpi_out,
                                               const int* __restrict__ gidx,
                                               const float* __restrict__ Wl1,
                                               const float* __restrict__ bnl1,
                                               const float* __restrict__ Wl2,
                                               const float* __restrict__ bnl2,
                                               const float* __restrict__ fpostT,
                                               const float* __restrict__ gfT,
                                               const float* __restrict__ idT,
                                               float* __restrict__ out_f) {
  __shared__ float loc1[NS_][32];
  __shared__ float dls[NS_][16];
  int gm = blockIdx.x;
  int b = gm >> 11, m = gm & 2047;
  int tid = threadIdx.x;
  const int* gx = gidx + gm * NS_;
  for (int i = tid; i < NS_ * 16; i += 128) {
    int s = i >> 4, c = i & 15;
    int j = gx[s];
    dls[s][c] = lp[(b * LPC_ + c) * NN + j] - lpi_out[(b * LPC_ + c) * MM + m];
  }
  __syncthreads();
  for (int i = tid; i < NS_ * 32; i += 128) {
    int s = i >> 5, o = i & 31;
    float a = 0.f;
    #pragma unroll
    for (int c = 0; c < 16; c++) a = fmaf(Wl1[o * 16 + c], dls[s][c], a);
    float ga = bnl1[o], be = bnl1[32 + o], mu = bnl1[64 + o], va = bnl1[96 + o];
    float sc = ga / sqrtf(va + EPSB);
    loc1[s][o] = fmaxf(a * sc + (be - mu * sc), 0.f);
  }
  __syncthreads();
  float wr[32];
  #pragma unroll
  for (int c = 0; c < 32; c++) wr[c] = Wl2[tid * 32 + c];
  float ga = bnl2[tid], be = bnl2[128 + tid], mu = bnl2[256 + tid], va = bnl2[384 + tid];
  float sc = ga / sqrtf(va + EPSB);
  float sh = be - mu * sc;
  float mx = -1e30f;
  for (int s = 0; s < NS_; s++) {
    float g = 0.f;
    #pragma unroll
    for (int c = 0; c < 32; c++) g = fmaf(wr[c], loc1[s][c], g);
    float l2 = fmaxf(g * sc + sh, 0.f);
    int j = gx[s];
    float fj = fpostT[(b * NN + j) * 128 + tid];
    mx = fmaxf(mx, fj + l2);
  }
  float fout = fmaxf(mx + gfT[gm * 128 + tid] + idT[gm * 128 + tid], 0.f);
  out_f[(b * COUT_ + tid) * MM + m] = fout;
}

// ------------------------------------------------------------------
extern "C" void kernel_launch(void* const* d_in, const int* in_sizes, int n_in,
                              void* d_out, int out_size, void* d_ws, size_t ws_size,
                              hipStream_t stream) {
  (void)in_sizes; (void)n_in; (void)out_size; (void)ws_size;
  const float* p      = (const float*)d_in[0];
  const float* lp     = (const float*)d_in[1];
  const float* f      = (const float*)d_in[2];
  const float* W_skip = (const float*)d_in[3];
  const float* b_skip = (const float*)d_in[4];
  const float* W_post = (const float*)d_in[5];
  const float* bn_post= (const float*)d_in[6];
  const float* W_loc1 = (const float*)d_in[7];
  const float* bn_loc1= (const float*)d_in[8];
  const float* W_loc2 = (const float*)d_in[9];
  const float* bn_loc2= (const float*)d_in[10];
  const float* W_g    = (const float*)d_in[11];
  const float* b_g    = (const float*)d_in[12];
  const float* W_v    = (const float*)d_in[13];
  const float* b_v    = (const float*)d_in[14];
  const float* W_w1   = (const float*)d_in[15];
  const float* bn_w1  = (const float*)d_in[16];
  const float* W_w2   = (const float*)d_in[17];
  const float* b_w2   = (const float*)d_in[18];
  const float* W_m    = (const float*)d_in[19];
  const float* bn_m   = (const float*)d_in[20];

  float* out = (float*)d_out;
  float* ws = (float*)d_ws;
  int*   idx    = (int*)(ws + WS_IDX);
  int*   idxk   = (int*)(ws + WS_IDXK);
  float* att    = ws + WS_ATT;
  float* fiT    = ws + WS_FIT;
  float* idT    = ws + WS_IDT;
  float* a1sT   = ws + WS_A1S;
  float* vT     = ws + WS_VT;
  float* b1sT   = ws + WS_B1S;
  float* gfT    = ws + WS_GFT;
  float* fpostT = ws + WS_FPOST;
  float* logit  = ws + WS_LOGIT;
  int*   gidx   = (int*)(ws + WS_GIDX);

  k_fps<<<BB, 1024, 0, stream>>>(p, idx, out + OUT_NEWP);
  k_fpost<<<(BB * NN * 16) / 256, 256, 0, stream>>>(f, W_post, bn_post, fpostT);
  k_gather<<<(BB * MM + 255) / 256, 256, 0, stream>>>(lp, f, idx, W_g, b_g, fiT, logit, att,
                                                      out + OUT_LPI);
  k_ident<<<(BB * MM * 16) / 256, 256, 0, stream>>>(fiT, W_skip, b_skip, idT);
  k_topk<<<BB, 1024, 0, stream>>>(att, idxk);
  k_a1s<<<(BB * MM + 255) / 256, 256, 0, stream>>>(fiT, att, W_w1, bn_w1, a1sT);
  k_vb1<<<(BB * KSEL + 255) / 256, 256, 0, stream>>>(fiT, idxk, W_v, b_v, W_w1, bn_w1, vT, b1sT);
  k_att<<<(BB * MM) / 4, 256, 0, stream>>>(a1sT, b1sT, vT, fiT, W_w2, b_w2, W_m, bn_m, gfT);
  k_ball<<<(BB * MM) / 4, 256, 0, stream>>>(p, out + OUT_NEWP, gidx);
  k_final<<<BB * MM, 128, 0, stream>>>(lp, out + OUT_LPI, gidx, W_loc1, bn_loc1, W_loc2, bn_loc2,
                                       fpostT, gfT, idT, out + OUT_F);
}

// Round 3
// 2802.940 us; speedup vs baseline: 1.1264x; 1.1264x over previous
//
#include <hip/hip_runtime.h>
#include <stdint.h>

#define BB 2
#define NN 8192
#define MM 2048
#define CIN_ 64
#define COUT_ 128
#define LPC_ 16
#define NS_ 32
#define KSEL 160
#define EPSB 1e-5f

// ws layout (float offsets)
#define WS_IDX    0         // int[B*M]
#define WS_IDXK   4096      // int[B*KSEL]
#define WS_LOGIT  4416      // f[B*M]
#define WS_ATT    8512      // f[B*M]
#define WS_FIT    16384     // f[B*M*64]
#define WS_IDT    278528    // f[B*M*128]
#define WS_A1S    802816    // f[B*M*16]
#define WS_VT     868352    // f[B*KSEL*64]
#define WS_B1S    888832    // f[B*KSEL*16]
#define WS_GFT    893952    // f[B*M*128]
#define WS_FPOST  1418240   // f[B*N*128]
#define WS_GIDX   3515392   // int[B*M*32]

#define OUT_NEWP 0
#define OUT_LPI  12288
#define OUT_F    77824

__device__ __forceinline__ float dist2_rn(float ax, float ay, float az,
                                          float bx, float by, float bz) {
  float dx = __fsub_rn(ax, bx);
  float dy = __fsub_rn(ay, by);
  float dz = __fsub_rn(az, bz);
  return __fadd_rn(__fadd_rn(__fmul_rn(dx, dx), __fmul_rn(dy, dy)), __fmul_rn(dz, dz));
}

// 64-bit max with one DPP step (VALU latency, not LDS-crossbar latency)
template <int CTRL>
__device__ __forceinline__ unsigned long long dppmax64(unsigned long long x) {
  unsigned lo = (unsigned)x, hi = (unsigned)(x >> 32);
  unsigned plo = (unsigned)__builtin_amdgcn_update_dpp(0, (int)lo, CTRL, 0xF, 0xF, true);
  unsigned phi = (unsigned)__builtin_amdgcn_update_dpp(0, (int)hi, CTRL, 0xF, 0xF, true);
  unsigned long long o = ((unsigned long long)phi << 32) | plo;
  return o > x ? o : x;
}
#define DPP_XOR1 0xB1   // quad_perm [1,0,3,2]
#define DPP_XOR2 0x4E   // quad_perm [2,3,0,1]
#define DPP_HALFMIR 0x141
#define DPP_MIR 0x140
#define DPP_BC15 0x142
#define DPP_BC31 0x143

// ------------------------------------------------------------------
// K1: fused FPS (blocks 0..1) + fpost (blocks 2..513).
// FPS: 512 threads = 8 waves, 16 points/thread, spatially sorted,
// bbox skip, DPP reductions, double-buffered slots, 1 barrier/step.
// ------------------------------------------------------------------
#define PPT 16
#define FPS_T 512
#define NWAVE 8

__global__ __launch_bounds__(FPS_T) void k_fps_fpost(const float* __restrict__ p,
                                                     int* __restrict__ idx_out,
                                                     float* __restrict__ newp_out,
                                                     const float* __restrict__ f,
                                                     const float* __restrict__ Wpost,
                                                     const float* __restrict__ bnpost,
                                                     float* __restrict__ fpostT) {
  __shared__ unsigned int hist[4096];
  __shared__ unsigned int perm[NN];
  __shared__ unsigned long long slots[2][NWAVE];
  __shared__ float4 slotc[2][NWAVE];
  __shared__ unsigned int wsum[NWAVE];

  if (blockIdx.x >= 2) {
    // ---------------- fpost path (runs concurrently with FPS) ----------
    int gt = (blockIdx.x - 2) * FPS_T + threadIdx.x;  // [0, BB*NN*16)
    int og = gt & 15, nn = gt >> 4;
    int b = nn >> 13, n = nn & 8191;
    const float* fb = f + b * CIN_ * NN + n;
    float acc[8];
    #pragma unroll
    for (int q = 0; q < 8; q++) acc[q] = 0.f;
    for (int c = 0; c < 64; c++) {
      float x = fb[c * NN];
      #pragma unroll
      for (int q = 0; q < 8; q++) acc[q] = fmaf(Wpost[(og * 8 + q) * 64 + c], x, acc[q]);
    }
    #pragma unroll
    for (int q = 0; q < 8; q++) {
      int o = og * 8 + q;
      float ga = bnpost[o], be = bnpost[COUT_ + o], mu = bnpost[2 * COUT_ + o],
            va = bnpost[3 * COUT_ + o];
      float sc = ga / sqrtf(va + EPSB);
      fpostT[(b * NN + n) * 128 + o] = fmaxf(acc[q] * sc + (be - mu * sc), 0.f);
    }
    return;
  }

  // ---------------- FPS path ----------------
  const int b = blockIdx.x;
  const float* pb = p + b * NN * 3;
  const int tid = threadIdx.x;
  const int lane = tid & 63;
  const int wid = tid >> 6;

  // --- 1. histogram of 16^3 cells ---
  for (int i = tid; i < 4096; i += FPS_T) hist[i] = 0u;
  __syncthreads();

  int cellv[PPT];
  #pragma unroll
  for (int k = 0; k < PPT; k++) {
    int i = tid + k * FPS_T;
    float x = pb[i * 3 + 0], y = pb[i * 3 + 1], z = pb[i * 3 + 2];
    int cx = (int)(x * 16.f); cx = cx < 0 ? 0 : (cx > 15 ? 15 : cx);
    int cy = (int)(y * 16.f); cy = cy < 0 ? 0 : (cy > 15 ? 15 : cy);
    int cz = (int)(z * 16.f); cz = cz < 0 ? 0 : (cz > 15 ? 15 : cz);
    int c = (cz * 16 + cy) * 16 + cx;
    cellv[k] = c;
    atomicAdd(&hist[c], 1u);
  }
  __syncthreads();

  // --- 2. exclusive scan over 4096 bins (thread owns 8) ---
  unsigned int h[8];
  unsigned int s = 0;
  #pragma unroll
  for (int k = 0; k < 8; k++) { h[k] = hist[tid * 8 + k]; s += h[k]; }
  unsigned int pre = s;
  for (int d = 1; d < 64; d <<= 1) {
    unsigned int o = (unsigned int)__shfl_up((int)pre, d);
    if (lane >= d) pre += o;
  }
  if (lane == 63) wsum[wid] = pre;
  __syncthreads();
  if (tid < NWAVE) {
    unsigned int v = wsum[tid];
    unsigned int q = v;
    for (int d = 1; d < NWAVE; d <<= 1) {
      unsigned int o = (unsigned int)__shfl_up((int)q, d);
      if (tid >= d) q += o;
    }
    wsum[tid] = q - v;  // exclusive
  }
  __syncthreads();
  unsigned int base = wsum[wid] + (pre - s);
  #pragma unroll
  for (int k = 0; k < 8; k++) {
    hist[tid * 8 + k] = base;
    base += h[k];
  }
  __syncthreads();

  // --- 3. scatter permutation ---
  #pragma unroll
  for (int k = 0; k < PPT; k++) {
    unsigned int pos = atomicAdd(&hist[cellv[k]], 1u);
    perm[pos] = (unsigned int)(tid + k * FPS_T);
  }
  __syncthreads();

  // --- 4. load sorted points into registers + bbox ---
  float sx[PPT], sy[PPT], sz[PPT], dist[PPT];
  unsigned int lov[PPT];
  float bxmin = 1e30f, bymin = 1e30f, bzmin = 1e30f;
  float bxmax = -1e30f, bymax = -1e30f, bzmax = -1e30f;
  #pragma unroll
  for (int q = 0; q < PPT; q++) {
    unsigned int o = perm[tid * PPT + q];
    float x = pb[o * 3 + 0], y = pb[o * 3 + 1], z = pb[o * 3 + 2];
    sx[q] = x; sy[q] = y; sz[q] = z;
    lov[q] = ((8191u - o) << 4) | (unsigned int)q;
    dist[q] = 1e10f;
    bxmin = fminf(bxmin, x); bxmax = fmaxf(bxmax, x);
    bymin = fminf(bymin, y); bymax = fmaxf(bymax, y);
    bzmin = fminf(bzmin, z); bzmax = fmaxf(bzmax, z);
  }

  // first winner: original index 0
  float wx = pb[0], wy = pb[1], wz = pb[2];
  if (tid == 0) {
    newp_out[(b * MM + 0) * 3 + 0] = wx;
    newp_out[(b * MM + 0) * 3 + 1] = wy;
    newp_out[(b * MM + 0) * 3 + 2] = wz;
    idx_out[b * MM + 0] = 0;
  }
  // thrPack starts with dist=1e10 so every lane is active at t=1.
  unsigned long long thrPack = ((unsigned long long)__float_as_uint(1e10f) << 32);
  unsigned long long wpCache = 0ull;
  float scX = 0.f, scY = 0.f, scZ = 0.f;
  bool isPub = false;
  __syncthreads();

  for (int t = 1; t < MM; t++) {
    const int buf = t & 1;
    // bbox-based exact skip test
    float ex = fmaxf(fmaxf(bxmin - wx, wx - bxmax), 0.f);
    float ey = fmaxf(fmaxf(bymin - wy, wy - bymax), 0.f);
    float ez = fmaxf(fmaxf(bzmin - wz, wz - bzmax), 0.f);
    float bd = (ex * ex + ey * ey + ez * ez) * 0.999f;  // conservative margin
    float thrMax = __uint_as_float((unsigned int)(thrPack >> 32));
    bool active = (bd < thrMax);
    unsigned long long wmask = __ballot(active);
    if (wmask) {
      if (active) {
        unsigned long long best = 0ull;
        #pragma unroll
        for (int q = 0; q < PPT; q++) {
          float d = dist2_rn(sx[q], sy[q], sz[q], wx, wy, wz);
          float nd = fminf(dist[q], d);
          dist[q] = nd;
          unsigned long long pk =
              ((unsigned long long)__float_as_uint(nd) << 32) | (unsigned long long)lov[q];
          best = pk > best ? pk : best;
        }
        thrPack = best;
      }
      // intra-wave max via DPP (VALU latency), result valid in lane 63
      unsigned long long wp = thrPack;
      wp = dppmax64<DPP_XOR1>(wp);
      wp = dppmax64<DPP_XOR2>(wp);
      wp = dppmax64<DPP_HALFMIR>(wp);
      wp = dppmax64<DPP_MIR>(wp);
      wp = dppmax64<DPP_BC15>(wp);
      wp = dppmax64<DPP_BC31>(wp);
      unsigned wlo = (unsigned)__builtin_amdgcn_readlane((int)(unsigned)wp, 63);
      unsigned whi = (unsigned)__builtin_amdgcn_readlane((int)(unsigned)(wp >> 32), 63);
      unsigned long long wmax = ((unsigned long long)whi << 32) | wlo;
      isPub = (thrPack == wmax);
      if (isPub) {
        wpCache = wmax;
        unsigned qs = (unsigned)(wmax & 15ull);
        #pragma unroll
        for (int q = 0; q < PPT; q++) {
          if (qs == (unsigned)q) { scX = sx[q]; scY = sy[q]; scZ = sz[q]; }
        }
      }
    }
    if (isPub) {
      slots[buf][wid] = wpCache;
      slotc[buf][wid] = make_float4(scX, scY, scZ, 0.f);
    }
    __syncthreads();  // the only barrier per step (slots double-buffered)

    int sidx = lane & (NWAVE - 1);
    unsigned long long sp = slots[buf][sidx];
    float4 sc = slotc[buf][sidx];
    unsigned long long w2 = sp;
    w2 = dppmax64<DPP_XOR1>(w2);
    w2 = dppmax64<DPP_XOR2>(w2);
    w2 = dppmax64<DPP_HALFMIR>(w2);  // all lanes now hold the global max
    unsigned long long bal = __ballot(sp == w2);
    int src = __ffsll(bal) - 1;
    wx = __shfl(sc.x, src);
    wy = __shfl(sc.y, src);
    wz = __shfl(sc.z, src);
    if (tid == 0) {
      int worig = 8191 - (int)((w2 >> 4) & 0x1FFFull);
      newp_out[(b * MM + t) * 3 + 0] = wx;
      newp_out[(b * MM + t) * 3 + 1] = wy;
      newp_out[(b * MM + t) * 3 + 2] = wz;
      idx_out[b * MM + t] = worig;
    }
  }
}

// ------------------------------------------------------------------
// K2a: gather lpi (to d_out), fi (transposed), logits + att
// ------------------------------------------------------------------
__global__ __launch_bounds__(256) void k_gather(const float* __restrict__ lp,
                                                const float* __restrict__ f,
                                                const int* __restrict__ idx,
                                                const float* __restrict__ Wg,
                                                const float* __restrict__ bg,
                                                float* __restrict__ fiT,
                                                float* __restrict__ logit,
                                                float* __restrict__ att,
                                                float* __restrict__ out_lpi) {
  int gm = blockIdx.x * 256 + threadIdx.x;
  if (gm >= BB * MM) return;
  int b = gm >> 11, m = gm & 2047;
  int j = idx[gm];
  const float* lpb = lp + b * LPC_ * NN;
  float* olpi = out_lpi + b * LPC_ * MM;
  #pragma unroll
  for (int c = 0; c < LPC_; c++) olpi[c * MM + m] = lpb[c * NN + j];
  const float* fb = f + b * CIN_ * NN;
  float lg = bg[0];
  #pragma unroll
  for (int c = 0; c < CIN_; c++) {
    float x = fb[c * NN + j];
    fiT[gm * 64 + c] = x;
    lg = __fadd_rn(lg, __fmul_rn(Wg[c], x));
  }
  logit[gm] = lg;
  att[gm] = 1.f / (1.f + expf(-lg));
}

// ------------------------------------------------------------------
// K2b: identity = W_skip @ fi + b_skip
// ------------------------------------------------------------------
__global__ __launch_bounds__(256) void k_ident(const float* __restrict__ fiT,
                                               const float* __restrict__ Wskip,
                                               const float* __restrict__ bskip,
                                               float* __restrict__ idT) {
  int gt = blockIdx.x * 256 + threadIdx.x;
  if (gt >= BB * MM * 16) return;
  int og = gt & 15, gm = gt >> 4;
  const float* fvp = fiT + gm * 64;
  float fv[64];
  #pragma unroll
  for (int c = 0; c < 64; c++) fv[c] = fvp[c];
  #pragma unroll
  for (int q = 0; q < 8; q++) {
    int o = og * 8 + q;
    float a = bskip[o];
    #pragma unroll
    for (int c = 0; c < 64; c++) a = fmaf(Wskip[o * 64 + c], fv[c], a);
    idT[gm * 128 + o] = a;
  }
}

// ------------------------------------------------------------------
// K3: top-160 per batch — bitonic sort of (att desc, idx asc) keys.
// ------------------------------------------------------------------
__global__ __launch_bounds__(1024) void k_topk(const float* __restrict__ att,
                                               int* __restrict__ idxk) {
  __shared__ unsigned long long key[MM];
  int b = blockIdx.x, tid = threadIdx.x;
  for (int i = tid; i < MM; i += 1024) {
    unsigned int u = __float_as_uint(att[b * MM + i]);
    u ^= (u & 0x80000000u) ? 0xFFFFFFFFu : 0x80000000u;  // monotone asc
    u = ~u;                                              // descending
    key[i] = ((unsigned long long)u << 32) | (unsigned int)i;
  }
  __syncthreads();
  for (int k = 2; k <= MM; k <<= 1) {
    for (int j = k >> 1; j > 0; j >>= 1) {
      for (int i = tid; i < MM; i += 1024) {
        int ixj = i ^ j;
        if (ixj > i) {
          bool up = (i & k) == 0;
          unsigned long long a = key[i], c = key[ixj];
          if ((a > c) == up) { key[i] = c; key[ixj] = a; }
        }
      }
      __syncthreads();
    }
  }
  if (tid < KSEL) idxk[b * KSEL + tid] = (int)(key[tid] & 0xFFFFFFFFull);
}

// ------------------------------------------------------------------
// K4a: A1s[c1,m] = s1*( (W_w1 @ (fi*att))[c1,m] ) + t1
// ------------------------------------------------------------------
__global__ __launch_bounds__(256) void k_a1s(const float* __restrict__ fiT,
                                             const float* __restrict__ att,
                                             const float* __restrict__ Ww1,
                                             const float* __restrict__ bnw1,
                                             float* __restrict__ a1sT) {
  int gm = blockIdx.x * 256 + threadIdx.x;
  if (gm >= BB * MM) return;
  const float* fvp = fiT + gm * 64;
  float a = att[gm];
  float fv[64];
  #pragma unroll
  for (int c = 0; c < 64; c++) fv[c] = fvp[c] * a;
  #pragma unroll
  for (int c1 = 0; c1 < 16; c1++) {
    float acc = 0.f;
    #pragma unroll
    for (int c = 0; c < 64; c++) acc = fmaf(Ww1[c1 * 64 + c], fv[c], acc);
    float g = bnw1[c1], be = bnw1[16 + c1], mu = bnw1[32 + c1], va = bnw1[48 + c1];
    float sc = g / sqrtf(va + EPSB);
    a1sT[gm * 16 + c1] = acc * sc + (be - mu * sc);
  }
}

// ------------------------------------------------------------------
// K4b: sparse columns -> v and B1s
// ------------------------------------------------------------------
__global__ __launch_bounds__(256) void k_vb1(const float* __restrict__ fiT,
                                             const int* __restrict__ idxk,
                                             const float* __restrict__ Wv,
                                             const float* __restrict__ bv,
                                             const float* __restrict__ Ww1,
                                             const float* __restrict__ bnw1,
                                             float* __restrict__ vT,
                                             float* __restrict__ b1sT) {
  int gk = blockIdx.x * 256 + threadIdx.x;
  if (gk >= BB * KSEL) return;
  int b = gk / KSEL;
  int kk = idxk[gk];
  const float* fvp = fiT + (b * MM + kk) * 64;
  float fv[64];
  #pragma unroll
  for (int c = 0; c < 64; c++) fv[c] = fvp[c];
  for (int o = 0; o < 64; o++) {
    float acc = bv[o];
    #pragma unroll
    for (int c = 0; c < 64; c++) acc = fmaf(Wv[o * 64 + c], fv[c], acc);
    vT[gk * 64 + o] = acc;
  }
  #pragma unroll
  for (int c1 = 0; c1 < 16; c1++) {
    float acc = 0.f;
    #pragma unroll
    for (int c = 0; c < 64; c++) acc = fmaf(Ww1[c1 * 64 + c], fv[c], acc);
    float g = bnw1[c1], va = bnw1[48 + c1];
    b1sT[gk * 16 + c1] = acc * (g / sqrtf(va + EPSB));
  }
}

// ------------------------------------------------------------------
// K5: fused attention epilogue + global_f.  one wave per (b,m), lane = c2
// ------------------------------------------------------------------
__global__ __launch_bounds__(256) void k_att(const float* __restrict__ a1sT,
                                             const float* __restrict__ b1sT,
                                             const float* __restrict__ vT,
                                             const float* __restrict__ fiT,
                                             const float* __restrict__ Ww2,
                                             const float* __restrict__ bw2,
                                             const float* __restrict__ Wm,
                                             const float* __restrict__ bnm,
                                             float* __restrict__ gfT) {
  __shared__ float B1sh[KSEL * 16];
  __shared__ float dsh[4][64];
  int b = blockIdx.x >> 9;
  const float* bsrc = b1sT + b * KSEL * 16;
  for (int i = threadIdx.x; i < KSEL * 16; i += 256) B1sh[i] = bsrc[i];
  __syncthreads();
  int wid = threadIdx.x >> 6, lane = threadIdx.x & 63;
  int gm = blockIdx.x * 4 + wid;
  int c15 = lane & 15;
  float a1 = a1sT[gm * 16 + c15];
  float wrow[16];
  #pragma unroll
  for (int c = 0; c < 16; c++) wrow[c] = Ww2[lane * 16 + c];
  float bw = bw2[lane];
  const float* vp = vT + b * KSEL * 64 + lane;
  float acc = 0.f;
  for (int k = 0; k < KSEL; k++) {
    float t = fmaxf(a1 - B1sh[k * 16 + c15], 0.f);
    float r2 = bw;
    #pragma unroll
    for (int c = 0; c < 16; c++) {
      float tc = __int_as_float(__builtin_amdgcn_readlane(__float_as_int(t), c));
      r2 = fmaf(wrow[c], tc, r2);
    }
    acc = fmaf(fmaxf(r2, 0.f), vp[k * 64], acc);
  }
  float af = acc * (1.f / (float)KSEL);
  float d = af - fiT[gm * 64 + lane];
  dsh[wid][lane] = d;
  __syncthreads();
  #pragma unroll
  for (int t2 = 0; t2 < 2; t2++) {
    int o = lane + t2 * 64;
    float g = 0.f;
    #pragma unroll
    for (int c = 0; c < 64; c++) g = fmaf(Wm[o * 64 + c], dsh[wid][c], g);
    float ga = bnm[o], be = bnm[COUT_ + o], mu = bnm[2 * COUT_ + o], va = bnm[3 * COUT_ + o];
    float sc = ga / sqrtf(va + EPSB);
    gfT[gm * 128 + o] = fmaxf(g * sc + (be - mu * sc), 0.f);
  }
}

// ------------------------------------------------------------------
// K7: ball query, one wave per (b,m)
// ------------------------------------------------------------------
__global__ __launch_bounds__(256) void k_ball(const float* __restrict__ p,
                                              const float* __restrict__ newp,
                                              int* __restrict__ gidx) {
  int wid = threadIdx.x >> 6, lane = threadIdx.x & 63;
  int gm = blockIdx.x * 4 + wid;
  int b = gm >> 11;
  const float* q = newp + gm * 3;
  float qx = q[0], qy = q[1], qz = q[2];
  const float* pb = p + b * NN * 3;
  int* out = gidx + gm * NS_;
  const float RR = (float)(0.1 * 0.1);
  int cnt = 0, firstj = 0;
  bool haveFirst = false;
  for (int chunk = 0; chunk < NN / 64 && cnt < NS_; chunk++) {
    int j = chunk * 64 + lane;
    float d = dist2_rn(qx, qy, qz, pb[j * 3], pb[j * 3 + 1], pb[j * 3 + 2]);
    unsigned long long mask = __ballot(d < RR);
    while (mask && cnt < NS_) {
      int l = __ffsll(mask) - 1;
      mask &= mask - 1;
      int jj = chunk * 64 + l;
      if (!haveFirst) { firstj = jj; haveFirst = true; }
      if (lane == 0) out[cnt] = jj;
      cnt++;
    }
  }
  if (lane == 0) {
    for (int i = cnt; i < NS_; i++) out[i] = firstj;
  }
}

// ------------------------------------------------------------------
// K8: grouped local conv + max + final combine -> d_out fout
// ------------------------------------------------------------------
__global__ __launch_bounds__(128) void k_final(const float* __restrict__ lp,
                                               const float* __restrict__ lpi_out,
                                               const int* __restrict__ gidx,
                                               const float* __restrict__ Wl1,
                                               const float* __restrict__ bnl1,
                                               const float* __restrict__ Wl2,
                                               const float* __restrict__ bnl2,
                                               const float* __restrict__ fpostT,
                                               const float* __restrict__ gfT,
                                               const float* __restrict__ idT,
                                               float* __restrict__ out_f) {
  __shared__ float loc1[NS_][32];
  __shared__ float dls[NS_][16];
  int gm = blockIdx.x;
  int b = gm >> 11, m = gm & 2047;
  int tid = threadIdx.x;
  const int* gx = gidx + gm * NS_;
  for (int i = tid; i < NS_ * 16; i += 128) {
    int s = i >> 4, c = i & 15;
    int j = gx[s];
    dls[s][c] = lp[(b * LPC_ + c) * NN + j] - lpi_out[(b * LPC_ + c) * MM + m];
  }
  __syncthreads();
  for (int i = tid; i < NS_ * 32; i += 128) {
    int s = i >> 5, o = i & 31;
    float a = 0.f;
    #pragma unroll
    for (int c = 0; c < 16; c++) a = fmaf(Wl1[o * 16 + c], dls[s][c], a);
    float ga = bnl1[o], be = bnl1[32 + o], mu = bnl1[64 + o], va = bnl1[96 + o];
    float sc = ga / sqrtf(va + EPSB);
    loc1[s][o] = fmaxf(a * sc + (be - mu * sc), 0.f);
  }
  __syncthreads();
  float wr[32];
  #pragma unroll
  for (int c = 0; c < 32; c++) wr[c] = Wl2[tid * 32 + c];
  float ga = bnl2[tid], be = bnl2[128 + tid], mu = bnl2[256 + tid], va = bnl2[384 + tid];
  float sc = ga / sqrtf(va + EPSB);
  float sh = be - mu * sc;
  float mx = -1e30f;
  for (int s = 0; s < NS_; s++) {
    float g = 0.f;
    #pragma unroll
    for (int c = 0; c < 32; c++) g = fmaf(wr[c], loc1[s][c], g);
    float l2 = fmaxf(g * sc + sh, 0.f);
    int j = gx[s];
    float fj = fpostT[(b * NN + j) * 128 + tid];
    mx = fmaxf(mx, fj + l2);
  }
  float fout = fmaxf(mx + gfT[gm * 128 + tid] + idT[gm * 128 + tid], 0.f);
  out_f[(b * COUT_ + tid) * MM + m] = fout;
}

// ------------------------------------------------------------------
extern "C" void kernel_launch(void* const* d_in, const int* in_sizes, int n_in,
                              void* d_out, int out_size, void* d_ws, size_t ws_size,
                              hipStream_t stream) {
  (void)in_sizes; (void)n_in; (void)out_size; (void)ws_size;
  const float* p      = (const float*)d_in[0];
  const float* lp     = (const float*)d_in[1];
  const float* f      = (const float*)d_in[2];
  const float* W_skip = (const float*)d_in[3];
  const float* b_skip = (const float*)d_in[4];
  const float* W_post = (const float*)d_in[5];
  const float* bn_post= (const float*)d_in[6];
  const float* W_loc1 = (const float*)d_in[7];
  const float* bn_loc1= (const float*)d_in[8];
  const float* W_loc2 = (const float*)d_in[9];
  const float* bn_loc2= (const float*)d_in[10];
  const float* W_g    = (const float*)d_in[11];
  const float* b_g    = (const float*)d_in[12];
  const float* W_v    = (const float*)d_in[13];
  const float* b_v    = (const float*)d_in[14];
  const float* W_w1   = (const float*)d_in[15];
  const float* bn_w1  = (const float*)d_in[16];
  const float* W_w2   = (const float*)d_in[17];
  const float* b_w2   = (const float*)d_in[18];
  const float* W_m    = (const float*)d_in[19];
  const float* bn_m   = (const float*)d_in[20];

  float* out = (float*)d_out;
  float* ws = (float*)d_ws;
  int*   idx    = (int*)(ws + WS_IDX);
  int*   idxk   = (int*)(ws + WS_IDXK);
  float* att    = ws + WS_ATT;
  float* fiT    = ws + WS_FIT;
  float* idT    = ws + WS_IDT;
  float* a1sT   = ws + WS_A1S;
  float* vT     = ws + WS_VT;
  float* b1sT   = ws + WS_B1S;
  float* gfT    = ws + WS_GFT;
  float* fpostT = ws + WS_FPOST;
  float* logit  = ws + WS_LOGIT;
  int*   gidx   = (int*)(ws + WS_GIDX);

  // blocks 0..1: FPS; blocks 2..513: fpost (runs on the idle CUs meanwhile)
  k_fps_fpost<<<2 + (BB * NN * 16) / FPS_T, FPS_T, 0, stream>>>(p, idx, out + OUT_NEWP, f,
                                                                W_post, bn_post, fpostT);
  k_gather<<<(BB * MM + 255) / 256, 256, 0, stream>>>(lp, f, idx, W_g, b_g, fiT, logit, att,
                                                      out + OUT_LPI);
  k_ident<<<(BB * MM * 16) / 256, 256, 0, stream>>>(fiT, W_skip, b_skip, idT);
  k_topk<<<BB, 1024, 0, stream>>>(att, idxk);
  k_a1s<<<(BB * MM + 255) / 256, 256, 0, stream>>>(fiT, att, W_w1, bn_w1, a1sT);
  k_vb1<<<(BB * KSEL + 255) / 256, 256, 0, stream>>>(fiT, idxk, W_v, b_v, W_w1, bn_w1, vT, b1sT);
  k_att<<<(BB * MM) / 4, 256, 0, stream>>>(a1sT, b1sT, vT, fiT, W_w2, b_w2, W_m, bn_m, gfT);
  k_ball<<<(BB * MM) / 4, 256, 0, stream>>>(p, out + OUT_NEWP, gidx);
  k_final<<<BB * MM, 128, 0, stream>>>(lp, out + OUT_LPI, gidx, W_loc1, bn_loc1, W_loc2, bn_loc2,
                                       fpostT, gfT, idT, out + OUT_F);
}

// Round 4
// 2777.440 us; speedup vs baseline: 1.1367x; 1.0092x over previous
//
#include <hip/hip_runtime.h>
#include <stdint.h>

#define BB 2
#define NN 8192
#define MM 2048
#define CIN_ 64
#define COUT_ 128
#define LPC_ 16
#define NS_ 32
#define KSEL 160
#define EPSB 1e-5f

// ws layout (float offsets)
#define WS_IDX    0         // int[B*M]
#define WS_IDXK   4096      // int[B*KSEL]
#define WS_LOGIT  4416      // f[B*M]
#define WS_ATT    8512      // f[B*M]
#define WS_FIT    16384     // f[B*M*64]
#define WS_IDT    278528    // f[B*M*128]
#define WS_A1S    802816    // f[B*M*16]
#define WS_VT     868352    // f[B*KSEL*64]
#define WS_B1S    888832    // f[B*KSEL*16]
#define WS_GFT    893952    // f[B*M*128]
#define WS_FPOST  1418240   // f[B*N*128]
#define WS_GIDX   3515392   // int[B*M*32]

#define OUT_NEWP 0
#define OUT_LPI  12288
#define OUT_F    77824

__device__ __forceinline__ float dist2_rn(float ax, float ay, float az,
                                          float bx, float by, float bz) {
  float dx = __fsub_rn(ax, bx);
  float dy = __fsub_rn(ay, by);
  float dz = __fsub_rn(az, bz);
  return __fadd_rn(__fadd_rn(__fmul_rn(dx, dx), __fmul_rn(dy, dy)), __fmul_rn(dz, dz));
}

// 64-bit max with one DPP step (VALU latency, not LDS-crossbar latency)
template <int CTRL>
__device__ __forceinline__ unsigned long long dppmax64(unsigned long long x) {
  unsigned lo = (unsigned)x, hi = (unsigned)(x >> 32);
  unsigned plo = (unsigned)__builtin_amdgcn_update_dpp(0, (int)lo, CTRL, 0xF, 0xF, true);
  unsigned phi = (unsigned)__builtin_amdgcn_update_dpp(0, (int)hi, CTRL, 0xF, 0xF, true);
  unsigned long long o = ((unsigned long long)phi << 32) | plo;
  return o > x ? o : x;
}
#define DPP_XOR1 0xB1   // quad_perm [1,0,3,2]
#define DPP_XOR2 0x4E   // quad_perm [2,3,0,1]
#define DPP_HALFMIR 0x141
#define DPP_MIR 0x140
#define DPP_BC15 0x142
#define DPP_BC31 0x143

// spread 4 bits to every 3rd bit position (for 16^3 Morton codes)
__device__ __forceinline__ unsigned mort4(unsigned x) {
  return (x & 1u) | ((x & 2u) << 2) | ((x & 4u) << 4) | ((x & 8u) << 6);
}

// ------------------------------------------------------------------
// K1: fused FPS (blocks 0..1) + fpost (blocks 2..).
// FPS: 512 threads = 8 waves, 16 points/thread, Morton-sorted (compact
// per-thread bbox -> strong skip), bbox skip, DPP reductions,
// double-buffered slots, 1 barrier/step.
// __launch_bounds__(512, 2): 256-VGPR cap so the 80-dword per-thread
// point/dist arrays stay in REGISTERS (rounds 2-3 spilled to scratch at
// VGPR=40/60 -> inner loop was scratch-latency-bound at ~3100 cy/step).
// ------------------------------------------------------------------
#define PPT 16
#define FPS_T 512
#define NWAVE 8

__global__ __launch_bounds__(FPS_T, 2) void k_fps_fpost(const float* __restrict__ p,
                                                        int* __restrict__ idx_out,
                                                        float* __restrict__ newp_out,
                                                        const float* __restrict__ f,
                                                        const float* __restrict__ Wpost,
                                                        const float* __restrict__ bnpost,
                                                        float* __restrict__ fpostT) {
  __shared__ unsigned int hist[4096];
  __shared__ unsigned int perm[NN];
  __shared__ unsigned long long slots[2][NWAVE];
  __shared__ float4 slotc[2][NWAVE];
  __shared__ unsigned int wsum[NWAVE];

  if (blockIdx.x >= 2) {
    // ---------------- fpost path (runs concurrently with FPS) ----------
    int gt = (blockIdx.x - 2) * FPS_T + threadIdx.x;  // [0, BB*NN*16)
    int og = gt & 15, nn = gt >> 4;
    int b = nn >> 13, n = nn & 8191;
    const float* fb = f + b * CIN_ * NN + n;
    float acc[8];
    #pragma unroll
    for (int q = 0; q < 8; q++) acc[q] = 0.f;
    for (int c = 0; c < 64; c++) {
      float x = fb[c * NN];
      #pragma unroll
      for (int q = 0; q < 8; q++) acc[q] = fmaf(Wpost[(og * 8 + q) * 64 + c], x, acc[q]);
    }
    #pragma unroll
    for (int q = 0; q < 8; q++) {
      int o = og * 8 + q;
      float ga = bnpost[o], be = bnpost[COUT_ + o], mu = bnpost[2 * COUT_ + o],
            va = bnpost[3 * COUT_ + o];
      float sc = ga / sqrtf(va + EPSB);
      fpostT[(b * NN + n) * 128 + o] = fmaxf(acc[q] * sc + (be - mu * sc), 0.f);
    }
    return;
  }

  // ---------------- FPS path ----------------
  const int b = blockIdx.x;
  const float* pb = p + b * NN * 3;
  const int tid = threadIdx.x;
  const int lane = tid & 63;
  const int wid = tid >> 6;

  // --- 1. histogram of 16^3 Morton cells ---
  for (int i = tid; i < 4096; i += FPS_T) hist[i] = 0u;
  __syncthreads();

  int cellv[PPT];
  #pragma unroll
  for (int k = 0; k < PPT; k++) {
    int i = tid + k * FPS_T;
    float x = pb[i * 3 + 0], y = pb[i * 3 + 1], z = pb[i * 3 + 2];
    int cx = (int)(x * 16.f); cx = cx < 0 ? 0 : (cx > 15 ? 15 : cx);
    int cy = (int)(y * 16.f); cy = cy < 0 ? 0 : (cy > 15 ? 15 : cy);
    int cz = (int)(z * 16.f); cz = cz < 0 ? 0 : (cz > 15 ? 15 : cz);
    int c = (int)(mort4((unsigned)cx) | (mort4((unsigned)cy) << 1) |
                  (mort4((unsigned)cz) << 2));
    cellv[k] = c;
    atomicAdd(&hist[c], 1u);
  }
  __syncthreads();

  // --- 2. exclusive scan over 4096 bins (thread owns 8) ---
  unsigned int h[8];
  unsigned int s = 0;
  #pragma unroll
  for (int k = 0; k < 8; k++) { h[k] = hist[tid * 8 + k]; s += h[k]; }
  unsigned int pre = s;
  for (int d = 1; d < 64; d <<= 1) {
    unsigned int o = (unsigned int)__shfl_up((int)pre, d);
    if (lane >= d) pre += o;
  }
  if (lane == 63) wsum[wid] = pre;
  __syncthreads();
  if (tid < NWAVE) {
    unsigned int v = wsum[tid];
    unsigned int q = v;
    for (int d = 1; d < NWAVE; d <<= 1) {
      unsigned int o = (unsigned int)__shfl_up((int)q, d);
      if (tid >= d) q += o;
    }
    wsum[tid] = q - v;  // exclusive
  }
  __syncthreads();
  unsigned int base = wsum[wid] + (pre - s);
  #pragma unroll
  for (int k = 0; k < 8; k++) {
    hist[tid * 8 + k] = base;
    base += h[k];
  }
  __syncthreads();

  // --- 3. scatter permutation ---
  #pragma unroll
  for (int k = 0; k < PPT; k++) {
    unsigned int pos = atomicAdd(&hist[cellv[k]], 1u);
    perm[pos] = (unsigned int)(tid + k * FPS_T);
  }
  __syncthreads();

  // --- 4. load sorted points into registers + bbox ---
  float sx[PPT], sy[PPT], sz[PPT], dist[PPT];
  unsigned int lov[PPT];
  float bxmin = 1e30f, bymin = 1e30f, bzmin = 1e30f;
  float bxmax = -1e30f, bymax = -1e30f, bzmax = -1e30f;
  #pragma unroll
  for (int q = 0; q < PPT; q++) {
    unsigned int o = perm[tid * PPT + q];
    float x = pb[o * 3 + 0], y = pb[o * 3 + 1], z = pb[o * 3 + 2];
    sx[q] = x; sy[q] = y; sz[q] = z;
    lov[q] = ((8191u - o) << 4) | (unsigned int)q;
    dist[q] = 1e10f;
    bxmin = fminf(bxmin, x); bxmax = fmaxf(bxmax, x);
    bymin = fminf(bymin, y); bymax = fmaxf(bymax, y);
    bzmin = fminf(bzmin, z); bzmax = fmaxf(bzmax, z);
  }

  // first winner: original index 0
  float wx = pb[0], wy = pb[1], wz = pb[2];
  if (tid == 0) {
    newp_out[(b * MM + 0) * 3 + 0] = wx;
    newp_out[(b * MM + 0) * 3 + 1] = wy;
    newp_out[(b * MM + 0) * 3 + 2] = wz;
    idx_out[b * MM + 0] = 0;
  }
  // thrPack starts with dist=1e10 so every lane is active at t=1.
  unsigned long long thrPack = ((unsigned long long)__float_as_uint(1e10f) << 32);
  unsigned long long wpCache = 0ull;
  float scX = 0.f, scY = 0.f, scZ = 0.f;
  bool isPub = false;
  __syncthreads();

  for (int t = 1; t < MM; t++) {
    const int buf = t & 1;
    // bbox-based exact skip test
    float ex = fmaxf(fmaxf(bxmin - wx, wx - bxmax), 0.f);
    float ey = fmaxf(fmaxf(bymin - wy, wy - bymax), 0.f);
    float ez = fmaxf(fmaxf(bzmin - wz, wz - bzmax), 0.f);
    float bd = (ex * ex + ey * ey + ez * ez) * 0.999f;  // conservative margin
    float thrMax = __uint_as_float((unsigned int)(thrPack >> 32));
    bool active = (bd < thrMax);
    unsigned long long wmask = __ballot(active);
    if (wmask) {
      if (active) {
        unsigned long long best = 0ull;
        #pragma unroll
        for (int q = 0; q < PPT; q++) {
          float d = dist2_rn(sx[q], sy[q], sz[q], wx, wy, wz);
          float nd = fminf(dist[q], d);
          dist[q] = nd;
          unsigned long long pk =
              ((unsigned long long)__float_as_uint(nd) << 32) | (unsigned long long)lov[q];
          best = pk > best ? pk : best;
        }
        thrPack = best;
      }
      // intra-wave max via DPP (VALU latency), result valid in lane 63
      unsigned long long wp = thrPack;
      wp = dppmax64<DPP_XOR1>(wp);
      wp = dppmax64<DPP_XOR2>(wp);
      wp = dppmax64<DPP_HALFMIR>(wp);
      wp = dppmax64<DPP_MIR>(wp);
      wp = dppmax64<DPP_BC15>(wp);
      wp = dppmax64<DPP_BC31>(wp);
      unsigned wlo = (unsigned)__builtin_amdgcn_readlane((int)(unsigned)wp, 63);
      unsigned whi = (unsigned)__builtin_amdgcn_readlane((int)(unsigned)(wp >> 32), 63);
      unsigned long long wmax = ((unsigned long long)whi << 32) | wlo;
      isPub = (thrPack == wmax);
      if (isPub) {
        wpCache = wmax;
        unsigned qs = (unsigned)(wmax & 15ull);
        #pragma unroll
        for (int q = 0; q < PPT; q++) {
          if (qs == (unsigned)q) { scX = sx[q]; scY = sy[q]; scZ = sz[q]; }
        }
      }
    }
    if (isPub) {
      slots[buf][wid] = wpCache;
      slotc[buf][wid] = make_float4(scX, scY, scZ, 0.f);
    }
    __syncthreads();  // the only barrier per step (slots double-buffered)

    int sidx = lane & (NWAVE - 1);
    unsigned long long sp = slots[buf][sidx];
    float4 sc = slotc[buf][sidx];
    unsigned long long w2 = sp;
    w2 = dppmax64<DPP_XOR1>(w2);
    w2 = dppmax64<DPP_XOR2>(w2);
    w2 = dppmax64<DPP_HALFMIR>(w2);  // all lanes now hold the global max
    unsigned long long bal = __ballot(sp == w2);
    int src = __ffsll(bal) - 1;
    wx = __shfl(sc.x, src);
    wy = __shfl(sc.y, src);
    wz = __shfl(sc.z, src);
    if (tid == 0) {
      int worig = 8191 - (int)((w2 >> 4) & 0x1FFFull);
      newp_out[(b * MM + t) * 3 + 0] = wx;
      newp_out[(b * MM + t) * 3 + 1] = wy;
      newp_out[(b * MM + t) * 3 + 2] = wz;
      idx_out[b * MM + t] = worig;
    }
  }
}

// ------------------------------------------------------------------
// K2a: gather lpi (to d_out), fi (transposed), logits + att
// ------------------------------------------------------------------
__global__ __launch_bounds__(256) void k_gather(const float* __restrict__ lp,
                                                const float* __restrict__ f,
                                                const int* __restrict__ idx,
                                                const float* __restrict__ Wg,
                                                const float* __restrict__ bg,
                                                float* __restrict__ fiT,
                                                float* __restrict__ logit,
                                                float* __restrict__ att,
                                                float* __restrict__ out_lpi) {
  int gm = blockIdx.x * 256 + threadIdx.x;
  if (gm >= BB * MM) return;
  int b = gm >> 11, m = gm & 2047;
  int j = idx[gm];
  const float* lpb = lp + b * LPC_ * NN;
  float* olpi = out_lpi + b * LPC_ * MM;
  #pragma unroll
  for (int c = 0; c < LPC_; c++) olpi[c * MM + m] = lpb[c * NN + j];
  const float* fb = f + b * CIN_ * NN;
  float lg = bg[0];
  #pragma unroll
  for (int c = 0; c < CIN_; c++) {
    float x = fb[c * NN + j];
    fiT[gm * 64 + c] = x;
    lg = __fadd_rn(lg, __fmul_rn(Wg[c], x));
  }
  logit[gm] = lg;
  att[gm] = 1.f / (1.f + expf(-lg));
}

// ------------------------------------------------------------------
// K2b: identity = W_skip @ fi + b_skip
// ------------------------------------------------------------------
__global__ __launch_bounds__(256) void k_ident(const float* __restrict__ fiT,
                                               const float* __restrict__ Wskip,
                                               const float* __restrict__ bskip,
                                               float* __restrict__ idT) {
  int gt = blockIdx.x * 256 + threadIdx.x;
  if (gt >= BB * MM * 16) return;
  int og = gt & 15, gm = gt >> 4;
  const float* fvp = fiT + gm * 64;
  float fv[64];
  #pragma unroll
  for (int c = 0; c < 64; c++) fv[c] = fvp[c];
  #pragma unroll
  for (int q = 0; q < 8; q++) {
    int o = og * 8 + q;
    float a = bskip[o];
    #pragma unroll
    for (int c = 0; c < 64; c++) a = fmaf(Wskip[o * 64 + c], fv[c], a);
    idT[gm * 128 + o] = a;
  }
}

// ------------------------------------------------------------------
// K3: top-160 per batch — bitonic sort of (att desc, idx asc) keys.
// ------------------------------------------------------------------
__global__ __launch_bounds__(1024) void k_topk(const float* __restrict__ att,
                                               int* __restrict__ idxk) {
  __shared__ unsigned long long key[MM];
  int b = blockIdx.x, tid = threadIdx.x;
  for (int i = tid; i < MM; i += 1024) {
    unsigned int u = __float_as_uint(att[b * MM + i]);
    u ^= (u & 0x80000000u) ? 0xFFFFFFFFu : 0x80000000u;  // monotone asc
    u = ~u;                                              // descending
    key[i] = ((unsigned long long)u << 32) | (unsigned int)i;
  }
  __syncthreads();
  for (int k = 2; k <= MM; k <<= 1) {
    for (int j = k >> 1; j > 0; j >>= 1) {
      for (int i = tid; i < MM; i += 1024) {
        int ixj = i ^ j;
        if (ixj > i) {
          bool up = (i & k) == 0;
          unsigned long long a = key[i], c = key[ixj];
          if ((a > c) == up) { key[i] = c; key[ixj] = a; }
        }
      }
      __syncthreads();
    }
  }
  if (tid < KSEL) idxk[b * KSEL + tid] = (int)(key[tid] & 0xFFFFFFFFull);
}

// ------------------------------------------------------------------
// K4a: A1s[c1,m] = s1*( (W_w1 @ (fi*att))[c1,m] ) + t1
// ------------------------------------------------------------------
__global__ __launch_bounds__(256) void k_a1s(const float* __restrict__ fiT,
                                             const float* __restrict__ att,
                                             const float* __restrict__ Ww1,
                                             const float* __restrict__ bnw1,
                                             float* __restrict__ a1sT) {
  int gm = blockIdx.x * 256 + threadIdx.x;
  if (gm >= BB * MM) return;
  const float* fvp = fiT + gm * 64;
  float a = att[gm];
  float fv[64];
  #pragma unroll
  for (int c = 0; c < 64; c++) fv[c] = fvp[c] * a;
  #pragma unroll
  for (int c1 = 0; c1 < 16; c1++) {
    float acc = 0.f;
    #pragma unroll
    for (int c = 0; c < 64; c++) acc = fmaf(Ww1[c1 * 64 + c], fv[c], acc);
    float g = bnw1[c1], be = bnw1[16 + c1], mu = bnw1[32 + c1], va = bnw1[48 + c1];
    float sc = g / sqrtf(va + EPSB);
    a1sT[gm * 16 + c1] = acc * sc + (be - mu * sc);
  }
}

// ------------------------------------------------------------------
// K4b: sparse columns -> v and B1s
// ------------------------------------------------------------------
__global__ __launch_bounds__(256) void k_vb1(const float* __restrict__ fiT,
                                             const int* __restrict__ idxk,
                                             const float* __restrict__ Wv,
                                             const float* __restrict__ bv,
                                             const float* __restrict__ Ww1,
                                             const float* __restrict__ bnw1,
                                             float* __restrict__ vT,
                                             float* __restrict__ b1sT) {
  int gk = blockIdx.x * 256 + threadIdx.x;
  if (gk >= BB * KSEL) return;
  int b = gk / KSEL;
  int kk = idxk[gk];
  const float* fvp = fiT + (b * MM + kk) * 64;
  float fv[64];
  #pragma unroll
  for (int c = 0; c < 64; c++) fv[c] = fvp[c];
  for (int o = 0; o < 64; o++) {
    float acc = bv[o];
    #pragma unroll
    for (int c = 0; c < 64; c++) acc = fmaf(Wv[o * 64 + c], fv[c], acc);
    vT[gk * 64 + o] = acc;
  }
  #pragma unroll
  for (int c1 = 0; c1 < 16; c1++) {
    float acc = 0.f;
    #pragma unroll
    for (int c = 0; c < 64; c++) acc = fmaf(Ww1[c1 * 64 + c], fv[c], acc);
    float g = bnw1[c1], va = bnw1[48 + c1];
    b1sT[gk * 16 + c1] = acc * (g / sqrtf(va + EPSB));
  }
}

// ------------------------------------------------------------------
// K5: fused attention epilogue + global_f.  one wave per (b,m), lane = c2
// ------------------------------------------------------------------
__global__ __launch_bounds__(256) void k_att(const float* __restrict__ a1sT,
                                             const float* __restrict__ b1sT,
                                             const float* __restrict__ vT,
                                             const float* __restrict__ fiT,
                                             const float* __restrict__ Ww2,
                                             const float* __restrict__ bw2,
                                             const float* __restrict__ Wm,
                                             const float* __restrict__ bnm,
                                             float* __restrict__ gfT) {
  __shared__ float B1sh[KSEL * 16];
  __shared__ float dsh[4][64];
  int b = blockIdx.x >> 9;
  const float* bsrc = b1sT + b * KSEL * 16;
  for (int i = threadIdx.x; i < KSEL * 16; i += 256) B1sh[i] = bsrc[i];
  __syncthreads();
  int wid = threadIdx.x >> 6, lane = threadIdx.x & 63;
  int gm = blockIdx.x * 4 + wid;
  int c15 = lane & 15;
  float a1 = a1sT[gm * 16 + c15];
  float wrow[16];
  #pragma unroll
  for (int c = 0; c < 16; c++) wrow[c] = Ww2[lane * 16 + c];
  float bw = bw2[lane];
  const float* vp = vT + b * KSEL * 64 + lane;
  float acc = 0.f;
  for (int k = 0; k < KSEL; k++) {
    float t = fmaxf(a1 - B1sh[k * 16 + c15], 0.f);
    float r2 = bw;
    #pragma unroll
    for (int c = 0; c < 16; c++) {
      float tc = __int_as_float(__builtin_amdgcn_readlane(__float_as_int(t), c));
      r2 = fmaf(wrow[c], tc, r2);
    }
    acc = fmaf(fmaxf(r2, 0.f), vp[k * 64], acc);
  }
  float af = acc * (1.f / (float)KSEL);
  float d = af - fiT[gm * 64 + lane];
  dsh[wid][lane] = d;
  __syncthreads();
  #pragma unroll
  for (int t2 = 0; t2 < 2; t2++) {
    int o = lane + t2 * 64;
    float g = 0.f;
    #pragma unroll
    for (int c = 0; c < 64; c++) g = fmaf(Wm[o * 64 + c], dsh[wid][c], g);
    float ga = bnm[o], be = bnm[COUT_ + o], mu = bnm[2 * COUT_ + o], va = bnm[3 * COUT_ + o];
    float sc = ga / sqrtf(va + EPSB);
    gfT[gm * 128 + o] = fmaxf(g * sc + (be - mu * sc), 0.f);
  }
}

// ------------------------------------------------------------------
// K7: ball query, one wave per (b,m)
// ------------------------------------------------------------------
__global__ __launch_bounds__(256) void k_ball(const float* __restrict__ p,
                                              const float* __restrict__ newp,
                                              int* __restrict__ gidx) {
  int wid = threadIdx.x >> 6, lane = threadIdx.x & 63;
  int gm = blockIdx.x * 4 + wid;
  int b = gm >> 11;
  const float* q = newp + gm * 3;
  float qx = q[0], qy = q[1], qz = q[2];
  const float* pb = p + b * NN * 3;
  int* out = gidx + gm * NS_;
  const float RR = (float)(0.1 * 0.1);
  int cnt = 0, firstj = 0;
  bool haveFirst = false;
  for (int chunk = 0; chunk < NN / 64 && cnt < NS_; chunk++) {
    int j = chunk * 64 + lane;
    float d = dist2_rn(qx, qy, qz, pb[j * 3], pb[j * 3 + 1], pb[j * 3 + 2]);
    unsigned long long mask = __ballot(d < RR);
    while (mask && cnt < NS_) {
      int l = __ffsll(mask) - 1;
      mask &= mask - 1;
      int jj = chunk * 64 + l;
      if (!haveFirst) { firstj = jj; haveFirst = true; }
      if (lane == 0) out[cnt] = jj;
      cnt++;
    }
  }
  if (lane == 0) {
    for (int i = cnt; i < NS_; i++) out[i] = firstj;
  }
}

// ------------------------------------------------------------------
// K8: grouped local conv + max + final combine -> d_out fout
// ------------------------------------------------------------------
__global__ __launch_bounds__(128) void k_final(const float* __restrict__ lp,
                                               const float* __restrict__ lpi_out,
                                               const int* __restrict__ gidx,
                                               const float* __restrict__ Wl1,
                                               const float* __restrict__ bnl1,
                                               const float* __restrict__ Wl2,
                                               const float* __restrict__ bnl2,
                                               const float* __restrict__ fpostT,
                                               const float* __restrict__ gfT,
                                               const float* __restrict__ idT,
                                               float* __restrict__ out_f) {
  __shared__ float loc1[NS_][32];
  __shared__ float dls[NS_][16];
  int gm = blockIdx.x;
  int b = gm >> 11, m = gm & 2047;
  int tid = threadIdx.x;
  const int* gx = gidx + gm * NS_;
  for (int i = tid; i < NS_ * 16; i += 128) {
    int s = i >> 4, c = i & 15;
    int j = gx[s];
    dls[s][c] = lp[(b * LPC_ + c) * NN + j] - lpi_out[(b * LPC_ + c) * MM + m];
  }
  __syncthreads();
  for (int i = tid; i < NS_ * 32; i += 128) {
    int s = i >> 5, o = i & 31;
    float a = 0.f;
    #pragma unroll
    for (int c = 0; c < 16; c++) a = fmaf(Wl1[o * 16 + c], dls[s][c], a);
    float ga = bnl1[o], be = bnl1[32 + o], mu = bnl1[64 + o], va = bnl1[96 + o];
    float sc = ga / sqrtf(va + EPSB);
    loc1[s][o] = fmaxf(a * sc + (be - mu * sc), 0.f);
  }
  __syncthreads();
  float wr[32];
  #pragma unroll
  for (int c = 0; c < 32; c++) wr[c] = Wl2[tid * 32 + c];
  float ga = bnl2[tid], be = bnl2[128 + tid], mu = bnl2[256 + tid], va = bnl2[384 + tid];
  float sc = ga / sqrtf(va + EPSB);
  float sh = be - mu * sc;
  float mx = -1e30f;
  for (int s = 0; s < NS_; s++) {
    float g = 0.f;
    #pragma unroll
    for (int c = 0; c < 32; c++) g = fmaf(wr[c], loc1[s][c], g);
    float l2 = fmaxf(g * sc + sh, 0.f);
    int j = gx[s];
    float fj = fpostT[(b * NN + j) * 128 + tid];
    mx = fmaxf(mx, fj + l2);
  }
  float fout = fmaxf(mx + gfT[gm * 128 + tid] + idT[gm * 128 + tid], 0.f);
  out_f[(b * COUT_ + tid) * MM + m] = fout;
}

// ------------------------------------------------------------------
extern "C" void kernel_launch(void* const* d_in, const int* in_sizes, int n_in,
                              void* d_out, int out_size, void* d_ws, size_t ws_size,
                              hipStream_t stream) {
  (void)in_sizes; (void)n_in; (void)out_size; (void)ws_size;
  const float* p      = (const float*)d_in[0];
  const float* lp     = (const float*)d_in[1];
  const float* f      = (const float*)d_in[2];
  const float* W_skip = (const float*)d_in[3];
  const float* b_skip = (const float*)d_in[4];
  const float* W_post = (const float*)d_in[5];
  const float* bn_post= (const float*)d_in[6];
  const float* W_loc1 = (const float*)d_in[7];
  const float* bn_loc1= (const float*)d_in[8];
  const float* W_loc2 = (const float*)d_in[9];
  const float* bn_loc2= (const float*)d_in[10];
  const float* W_g    = (const float*)d_in[11];
  const float* b_g    = (const float*)d_in[12];
  const float* W_v    = (const float*)d_in[13];
  const float* b_v    = (const float*)d_in[14];
  const float* W_w1   = (const float*)d_in[15];
  const float* bn_w1  = (const float*)d_in[16];
  const float* W_w2   = (const float*)d_in[17];
  const float* b_w2   = (const float*)d_in[18];
  const float* W_m    = (const float*)d_in[19];
  const float* bn_m   = (const float*)d_in[20];

  float* out = (float*)d_out;
  float* ws = (float*)d_ws;
  int*   idx    = (int*)(ws + WS_IDX);
  int*   idxk   = (int*)(ws + WS_IDXK);
  float* att    = ws + WS_ATT;
  float* fiT    = ws + WS_FIT;
  float* idT    = ws + WS_IDT;
  float* a1sT   = ws + WS_A1S;
  float* vT     = ws + WS_VT;
  float* b1sT   = ws + WS_B1S;
  float* gfT    = ws + WS_GFT;
  float* fpostT = ws + WS_FPOST;
  float* logit  = ws + WS_LOGIT;
  int*   gidx   = (int*)(ws + WS_GIDX);

  // blocks 0..1: FPS; blocks 2..513: fpost (runs on the idle CUs meanwhile)
  k_fps_fpost<<<2 + (BB * NN * 16) / FPS_T, FPS_T, 0, stream>>>(p, idx, out + OUT_NEWP, f,
                                                                W_post, bn_post, fpostT);
  k_gather<<<(BB * MM + 255) / 256, 256, 0, stream>>>(lp, f, idx, W_g, b_g, fiT, logit, att,
                                                      out + OUT_LPI);
  k_ident<<<(BB * MM * 16) / 256, 256, 0, stream>>>(fiT, W_skip, b_skip, idT);
  k_topk<<<BB, 1024, 0, stream>>>(att, idxk);
  k_a1s<<<(BB * MM + 255) / 256, 256, 0, stream>>>(fiT, att, W_w1, bn_w1, a1sT);
  k_vb1<<<(BB * KSEL + 255) / 256, 256, 0, stream>>>(fiT, idxk, W_v, b_v, W_w1, bn_w1, vT, b1sT);
  k_att<<<(BB * MM) / 4, 256, 0, stream>>>(a1sT, b1sT, vT, fiT, W_w2, b_w2, W_m, bn_m, gfT);
  k_ball<<<(BB * MM) / 4, 256, 0, stream>>>(p, out + OUT_NEWP, gidx);
  k_final<<<BB * MM, 128, 0, stream>>>(lp, out + OUT_LPI, gidx, W_loc1, bn_loc1, W_loc2, bn_loc2,
                                       fpostT, gfT, idT, out + OUT_F);
}